// Round 10
// baseline (169.625 us; speedup 1.0000x reference)
//
#include <hip/hip_runtime.h>
#include <math.h>

#define Bz 32
#define Sz 4096
#define Hz 32
#define Gz 2
#define Dz 128
#define HIDz 4096
#define QKVz 4608
#define NCHc 16   // combine chunks per (b,g) = blocks; block span <= 256 rows

static __device__ __forceinline__ void fma4(float4& a, float s, const float4& v) {
  a.x = fmaf(s, v.x, a.x);
  a.y = fmaf(s, v.y, a.y);
  a.z = fmaf(s, v.z, a.z);
  a.w = fmaf(s, v.w, a.w);
}
static __device__ __forceinline__ float dot4(const float4& a, const float4& b, float acc) {
  return fmaf(a.x, b.x, fmaf(a.y, b.y, fmaf(a.z, b.z, fmaf(a.w, b.w, acc))));
}
// direct HBM->LDS, 16 B per lane (wave-uniform LDS base + lane*16 by construction)
static __device__ __forceinline__ void gload16(const float* src, float* ldst) {
  __builtin_amdgcn_global_load_lds(
      (const __attribute__((address_space(1))) void*)src,
      (__attribute__((address_space(3))) void*)ldst, 16, 0, 0);
}

// ---------------- split-K GEMM partial: part[kt][b][j] = sum_{k in chunk} X[b][k]*W[k][j]
__global__ __launch_bounds__(256) void gemm_partial(
    const float* __restrict__ X, const float* __restrict__ W,
    float* __restrict__ part, int K, int N, int KH) {
  extern __shared__ float hl[];  // [32][KH+4]
  const int stride = KH + 4;
  const int t = threadIdx.x;
  const int k0 = blockIdx.y * KH;
  const int cols4 = KH >> 2;
  const int total4 = Bz * cols4;
  for (int fi = t; fi < total4; fi += 256) {
    const int row = fi / cols4;
    const int c4 = fi - row * cols4;
    const float4 v = *(const float4*)&X[(size_t)row * K + k0 + c4 * 4];
    *(float4*)&hl[row * stride + c4 * 4] = v;
  }
  __syncthreads();
  const int jl = t & 31;
  const int b0 = (t >> 5) * 4;
  const int j = blockIdx.x * 128 + jl * 4;
  float4 acc[4];
  #pragma unroll
  for (int i = 0; i < 4; i++) acc[i] = make_float4(0.f, 0.f, 0.f, 0.f);
  #pragma unroll 4
  for (int kk = 0; kk < KH; kk += 4) {
    const float4 w0 = *(const float4*)&W[(size_t)(k0 + kk + 0) * N + j];
    const float4 w1 = *(const float4*)&W[(size_t)(k0 + kk + 1) * N + j];
    const float4 w2 = *(const float4*)&W[(size_t)(k0 + kk + 2) * N + j];
    const float4 w3 = *(const float4*)&W[(size_t)(k0 + kk + 3) * N + j];
    #pragma unroll
    for (int bi = 0; bi < 4; bi++) {
      const float4 hb = *(const float4*)&hl[(b0 + bi) * stride + kk];
      fma4(acc[bi], hb.x, w0);
      fma4(acc[bi], hb.y, w1);
      fma4(acc[bi], hb.z, w2);
      fma4(acc[bi], hb.w, w3);
    }
  }
  #pragma unroll
  for (int bi = 0; bi < 4; bi++) {
    *(float4*)&part[((size_t)blockIdx.y * Bz + b0 + bi) * N + j] = acc[bi];
  }
}

// ---------------- reduce QKV partials + bias, RoPE, emit qrot (pre-scaled), krot, vnew
__global__ __launch_bounds__(256) void qkv_finish(
    const float* __restrict__ part, const float* __restrict__ bias,
    const int* __restrict__ positions, int KT,
    float* __restrict__ qrot, float* __restrict__ krot, float* __restrict__ vnew) {
  const int t = threadIdx.x;
  const int b = blockIdx.x;
  const int head = blockIdx.y * 4 + (t >> 6);
  const int tp = t & 63;
  const int j0 = head * Dz + tp * 2;
  float s0 = bias[j0];
  float s1 = bias[j0 + 1];
  for (int kt = 0; kt < KT; kt++) {
    const float2 p = *(const float2*)&part[((size_t)kt * Bz + b) * QKVz + j0];
    s0 += p.x;
    s1 += p.y;
  }
  float o0 = s0, o1 = s1;
  if (head < Hz + Gz && tp < 32) {
    const float invf = exp2f(-(float)tp * (13.287712379549449f / 32.0f));
    const float a = (float)positions[b] * invf;
    float sn, cs;
    sincosf(a, &sn, &cs);
    o0 = s0 * cs - s1 * sn;
    o1 = s1 * cs + s0 * sn;
  }
  if (head < Hz) {
    const float sc = 0.08838834764831845f;
    float2 o = make_float2(o0 * sc, o1 * sc);
    *(float2*)&qrot[((size_t)b * Hz + head) * Dz + tp * 2] = o;
  } else if (head < Hz + Gz) {
    float2 o = make_float2(o0, o1);
    *(float2*)&krot[((size_t)b * Gz + (head - Hz)) * Dz + tp * 2] = o;
  } else {
    float2 o = make_float2(s0, s1);
    *(float2*)&vnew[((size_t)b * Gz + (head - Hz - Gz)) * Dz + tp * 2] = o;
  }
}

// ---------------- flash block: block bx owns contiguous balanced span
// [bx*(pos+1)/16, (bx+1)*(pos+1)/16), processed in 32-row K/V tiles staged via
// global_load_lds (double-buffered). Wave w owns rows [w*8, w*8+8) of each tile.
// QK lane = (s8 = lane>>3, c8 = lane&7): 4 K b128 (even bank spread) x 16 heads from
// transposed Qt. PV lane owns d-pair (2*lane): V b64 full-row reads; P via per-wave LDS
// single-address broadcasts. grid (16, G, B), block 256.
__global__ __launch_bounds__(256, 2) void attn_unit(
    const float* __restrict__ qrot, const float* __restrict__ kcache,
    const float* __restrict__ vcache, const float* __restrict__ krot,
    const float* __restrict__ vnew, const int* __restrict__ positions,
    float* __restrict__ mbuf, float* __restrict__ lbuf, float* __restrict__ pacc) {
  __shared__ float kb[2][4096];   // 2 x 16 KB, rows x 128 (linear for gload_lds)
  __shared__ float vb[2][4096];
  __shared__ float qt[2176];      // Qt[c in 0..31][h in 0..15][4] stride 68 (bank-spread)
  __shared__ float pl[4][160];    // per wave: [8 rows][20]
  __shared__ float ml[128];
  const int g = blockIdx.y, b = blockIdx.z, bx = blockIdx.x;
  const int pos = positions[b];
  const int lt = pos + 1;
  const int blo = (bx * lt) >> 4;
  const int bhi = ((bx + 1) * lt) >> 4;
  const int nr = bhi - blo;                 // contiguous valid rows (block-uniform)
  const int ntile = (nr + 31) >> 5;
  const int t = threadIdx.x;
  const int w = t >> 6, lane = t & 63;
  const int s8 = lane >> 3, c8 = lane & 7;

  // Qt build (Q pre-scaled by D^-0.5)
  for (int i = t; i < 512; i += 256) {
    const int c = i >> 4, h = i & 15;
    const float4 q = *(const float4*)&qrot[((size_t)b * Hz + g * 16 + h) * Dz + c * 4];
    *(float4*)&qt[c * 68 + h * 4] = q;
  }

  const float* krow_new = &krot[((size_t)b * Gz + g) * Dz];
  const float* vrow_new = &vnew[((size_t)b * Gz + g) * Dz];
  const size_t kvb = ((size_t)b * Sz) * (Gz * Dz) + (size_t)g * Dz;

#define STAGE(tile, buf)                                                          \
  { _Pragma("unroll") for (int r4 = 0; r4 < 4; ++r4) {                            \
      const int sg = blo + (tile) * 32 + r4 * 8 + (t >> 5);                       \
      const bool fresh = (sg >= bhi) || (sg == pos);                              \
      const float* kp = fresh ? krow_new : &kcache[kvb + (size_t)sg * (Gz * Dz)]; \
      const float* vp = fresh ? vrow_new : &vcache[kvb + (size_t)sg * (Gz * Dz)]; \
      gload16(kp + (t & 31) * 4, &kb[buf][r4 * 1024 + t * 4]);                    \
      gload16(vp + (t & 31) * 4, &vb[buf][r4 * 1024 + t * 4]); } }

  float m_run[16], l_run[16];
  float2 A2[16];
  #pragma unroll
  for (int h = 0; h < 16; ++h) {
    m_run[h] = -1e30f;
    l_run[h] = 0.f;
    A2[h] = make_float2(0.f, 0.f);
  }

  int cur = 0;
  if (ntile > 0) STAGE(0, 0);
  __syncthreads();  // drains vmcnt(0) + barrier (covers Qt build too)

  for (int tile = 0; tile < ntile; ++tile) {
    if (tile + 1 < ntile) STAGE(tile + 1, cur ^ 1);  // in flight under compute
    const int rbase = tile * 32 + w * 8;
    const bool valid = (rbase + s8) < nr;

    // ---- QK: lane (s8,c8): K slots {c8+8it}, 16 heads each
    float lp[16];
    #pragma unroll
    for (int h = 0; h < 16; ++h) lp[h] = 0.f;
    float4 kf[4];
    #pragma unroll
    for (int it = 0; it < 4; ++it)
      kf[it] = *(const float4*)&kb[cur][(w * 8 + s8) * 128 + (c8 + it * 8) * 4];
    #pragma unroll
    for (int it = 0; it < 4; ++it) {
      #pragma unroll
      for (int h = 0; h < 16; ++h) {
        const float4 qv = *(const float4*)&qt[(c8 + it * 8) * 68 + h * 4];
        lp[h] = dot4(qv, kf[it], lp[h]);
      }
    }
    // reduce over c8 lanes (bits 0..2)
    #pragma unroll
    for (int h = 0; h < 16; ++h) {
      lp[h] += __shfl_xor(lp[h], 1);
      lp[h] += __shfl_xor(lp[h], 2);
      lp[h] += __shfl_xor(lp[h], 4);
    }
    // ---- online softmax per head (row-max over s8 bits 3..5)
    #pragma unroll
    for (int h = 0; h < 16; ++h) {
      const float lg = valid ? lp[h] : -1e30f;
      float v = lg;
      v = fmaxf(v, __shfl_xor(v, 8));
      v = fmaxf(v, __shfl_xor(v, 16));
      v = fmaxf(v, __shfl_xor(v, 32));
      const float mn = fmaxf(m_run[h], v);
      const float sc = __expf(m_run[h] - mn);
      m_run[h] = mn;
      const float p = valid ? __expf(lg - mn) : 0.f;
      float ts = p;
      ts += __shfl_xor(ts, 8);
      ts += __shfl_xor(ts, 16);
      ts += __shfl_xor(ts, 32);
      l_run[h] = l_run[h] * sc + ts;
      A2[h].x *= sc;
      A2[h].y *= sc;
      lp[h] = p;
    }
    // ---- P handoff (wave-private; c8==0 lanes write row s8)
    if (c8 == 0) {
      float* pr = &pl[w][s8 * 20];
      *(float4*)&pr[0] = make_float4(lp[0], lp[1], lp[2], lp[3]);
      *(float4*)&pr[4] = make_float4(lp[4], lp[5], lp[6], lp[7]);
      *(float4*)&pr[8] = make_float4(lp[8], lp[9], lp[10], lp[11]);
      *(float4*)&pr[12] = make_float4(lp[12], lp[13], lp[14], lp[15]);
    }
    // ---- PV: lane owns d-pair {2*lane, 2*lane+1}
    #pragma unroll
    for (int s = 0; s < 8; ++s) {
      const float2 v2 = *(const float2*)&vb[cur][(w * 8 + s) * 128 + lane * 2];
      const float4 p0 = *(const float4*)&pl[w][s * 20 + 0];
      const float4 p1 = *(const float4*)&pl[w][s * 20 + 4];
      const float4 p2 = *(const float4*)&pl[w][s * 20 + 8];
      const float4 p3 = *(const float4*)&pl[w][s * 20 + 12];
      A2[0].x = fmaf(p0.x, v2.x, A2[0].x);  A2[0].y = fmaf(p0.x, v2.y, A2[0].y);
      A2[1].x = fmaf(p0.y, v2.x, A2[1].x);  A2[1].y = fmaf(p0.y, v2.y, A2[1].y);
      A2[2].x = fmaf(p0.z, v2.x, A2[2].x);  A2[2].y = fmaf(p0.z, v2.y, A2[2].y);
      A2[3].x = fmaf(p0.w, v2.x, A2[3].x);  A2[3].y = fmaf(p0.w, v2.y, A2[3].y);
      A2[4].x = fmaf(p1.x, v2.x, A2[4].x);  A2[4].y = fmaf(p1.x, v2.y, A2[4].y);
      A2[5].x = fmaf(p1.y, v2.x, A2[5].x);  A2[5].y = fmaf(p1.y, v2.y, A2[5].y);
      A2[6].x = fmaf(p1.z, v2.x, A2[6].x);  A2[6].y = fmaf(p1.z, v2.y, A2[6].y);
      A2[7].x = fmaf(p1.w, v2.x, A2[7].x);  A2[7].y = fmaf(p1.w, v2.y, A2[7].y);
      A2[8].x = fmaf(p2.x, v2.x, A2[8].x);  A2[8].y = fmaf(p2.x, v2.y, A2[8].y);
      A2[9].x = fmaf(p2.y, v2.x, A2[9].x);  A2[9].y = fmaf(p2.y, v2.y, A2[9].y);
      A2[10].x = fmaf(p2.z, v2.x, A2[10].x); A2[10].y = fmaf(p2.z, v2.y, A2[10].y);
      A2[11].x = fmaf(p2.w, v2.x, A2[11].x); A2[11].y = fmaf(p2.w, v2.y, A2[11].y);
      A2[12].x = fmaf(p3.x, v2.x, A2[12].x); A2[12].y = fmaf(p3.x, v2.y, A2[12].y);
      A2[13].x = fmaf(p3.y, v2.x, A2[13].x); A2[13].y = fmaf(p3.y, v2.y, A2[13].y);
      A2[14].x = fmaf(p3.z, v2.x, A2[14].x); A2[14].y = fmaf(p3.z, v2.y, A2[14].y);
      A2[15].x = fmaf(p3.w, v2.x, A2[15].x); A2[15].y = fmaf(p3.w, v2.y, A2[15].y);
    }
    __syncthreads();  // drain staging vmcnt + release buffers
    cur ^= 1;
  }

  // ---- in-block combine (m/l wave-uniform across lanes)
  if (lane == 0) {
    #pragma unroll
    for (int h = 0; h < 16; h += 4) {
      *(float4*)&ml[w * 32 + h] = make_float4(m_run[h], m_run[h + 1], m_run[h + 2], m_run[h + 3]);
      *(float4*)&ml[w * 32 + 16 + h] =
          make_float4(l_run[h], l_run[h + 1], l_run[h + 2], l_run[h + 3]);
    }
  }
  __syncthreads();
  float ew[16];
  #pragma unroll
  for (int h = 0; h < 16; ++h) {
    const float ms = fmaxf(fmaxf(ml[h], ml[32 + h]), fmaxf(ml[64 + h], ml[96 + h]));
    ew[h] = __expf(m_run[h] - ms);
  }
  float* Aw = kb[0];  // 16 x 132
  for (int step = 0; step < 4; ++step) {
    if (w == step) {
      #pragma unroll
      for (int h = 0; h < 16; ++h) {
        float2 x;
        if (step == 0) {
          x = make_float2(ew[h] * A2[h].x, ew[h] * A2[h].y);
        } else {
          x = *(const float2*)&Aw[h * 132 + lane * 2];
          x.x = fmaf(ew[h], A2[h].x, x.x);
          x.y = fmaf(ew[h], A2[h].y, x.y);
        }
        *(float2*)&Aw[h * 132 + lane * 2] = x;
      }
    }
    __syncthreads();
  }
  const size_t cb = (size_t)(b * Gz + g) * NCHc + bx;
  for (int o = t; o < 512; o += 256) {
    const int hh = o >> 5, d4c = o & 31;
    *(float4*)&pacc[cb * 2048 + (size_t)hh * Dz + d4c * 4] =
        *(const float4*)&Aw[hh * 132 + d4c * 4];
  }
  if (t < 16) {
    const int hh = t;
    const float m0 = ml[hh], m1 = ml[32 + hh], m2 = ml[64 + hh], m3 = ml[96 + hh];
    const float msf = fmaxf(fmaxf(m0, m1), fmaxf(m2, m3));
    const float l = __expf(m0 - msf) * ml[16 + hh] + __expf(m1 - msf) * ml[48 + hh] +
                    __expf(m2 - msf) * ml[80 + hh] + __expf(m3 - msf) * ml[112 + hh];
    mbuf[cb * 16 + hh] = msf;
    lbuf[cb * 16 + hh] = l;
  }
#undef STAGE
}

// ---------------- combine chunk partials -> ctx (B, H*D)
__global__ __launch_bounds__(512) void attn_combine(
    const float* __restrict__ mbuf, const float* __restrict__ lbuf,
    const float* __restrict__ pacc, const int* __restrict__ positions,
    float* __restrict__ ctx) {
  const int bg = blockIdx.x;
  const int b = bg >> 1, g = bg & 1;
  const int t = threadIdx.x;
  const int h = t >> 5, dg = t & 31;
  const size_t mlb = (size_t)bg * NCHc * 16 + h;
  float mstar = -1e30f;
  for (int c = 0; c < NCHc; c++) mstar = fmaxf(mstar, mbuf[mlb + c * 16]);
  float lsum = 0.f;
  float4 A = make_float4(0.f, 0.f, 0.f, 0.f);
  for (int c = 0; c < NCHc; c++) {
    const float wv = __expf(mbuf[mlb + c * 16] - mstar);
    lsum += wv * lbuf[mlb + c * 16];
    const float4 p = *(const float4*)&pacc[((size_t)bg * NCHc + c) * 2048 + (size_t)h * Dz + dg * 4];
    fma4(A, wv, p);
  }
  const float inv = 1.0f / lsum;
  float4 o = make_float4(A.x * inv, A.y * inv, A.z * inv, A.w * inv);
  *(float4*)&ctx[(size_t)b * (Hz * Dz) + (g * 16 + h) * Dz + dg * 4] = o;
}

// ---------------- reduce dense partials -> out
__global__ __launch_bounds__(256) void reduce_out(
    const float* __restrict__ part, float* __restrict__ out, int KT) {
  const int idx = blockIdx.x * 256 + threadIdx.x;
  const int b = idx >> 12;
  const int j = idx & 4095;
  float s = 0.f;
  for (int kt = 0; kt < KT; kt++) s += part[((size_t)kt * Bz + b) * HIDz + j];
  out[idx] = s;
}

extern "C" void kernel_launch(void* const* d_in, const int* in_sizes, int n_in,
                              void* d_out, int out_size, void* d_ws, size_t ws_size,
                              hipStream_t stream) {
  const float* hidden = (const float*)d_in[0];
  const int* positions = (const int*)d_in[1];
  const float* kcache = (const float*)d_in[2];
  const float* vcache = (const float*)d_in[3];
  const float* Wqkv = (const float*)d_in[4];
  const float* bqkv = (const float*)d_in[5];
  const float* Wd = (const float*)d_in[6];
  float* out = (float*)d_out;

  auto need = [](int KT) -> size_t {
    return (size_t)KT * Bz * QKVz
         + (size_t)Bz * Hz * Dz
         + (size_t)Bz * Gz * Dz * 2
         + (size_t)Bz * Gz * NCHc * 16 * 2
         + (size_t)Bz * Gz * NCHc * 2048
         + (size_t)Bz * HIDz;
  };
  int KT = 32;
  if (need(32) * sizeof(float) > ws_size) KT = 16;
  const int KH = HIDz / KT;

  float* w = (float*)d_ws;
  float* p1 = w;    w += (size_t)KT * Bz * QKVz;
  float* qrot = w;  w += (size_t)Bz * Hz * Dz;
  float* krot = w;  w += (size_t)Bz * Gz * Dz;
  float* vnew = w;  w += (size_t)Bz * Gz * Dz;
  float* mbuf = w;  w += (size_t)Bz * Gz * NCHc * 16;
  float* lbuf = w;  w += (size_t)Bz * Gz * NCHc * 16;
  float* pacc = w;  w += (size_t)Bz * Gz * NCHc * 2048;
  float* ctx = w;

  const size_t smem = (size_t)Bz * (KH + 4) * sizeof(float);

  gemm_partial<<<dim3(QKVz / 128, KT), 256, smem, stream>>>(hidden, Wqkv, p1, HIDz, QKVz, KH);
  qkv_finish<<<dim3(Bz, 9), 256, 0, stream>>>(p1, bqkv, positions, KT, qrot, krot, vnew);
  attn_unit<<<dim3(NCHc, Gz, Bz), 256, 0, stream>>>(qrot, kcache, vcache, krot, vnew, positions,
                                                    mbuf, lbuf, pacc);
  attn_combine<<<dim3(Bz * Gz), 512, 0, stream>>>(mbuf, lbuf, pacc, positions, ctx);
  gemm_partial<<<dim3(HIDz / 128, KT), 256, smem, stream>>>(ctx, Wd, p1, Hz * Dz, HIDz, KH);
  reduce_out<<<dim3(Bz * HIDz / 256), 256, 0, stream>>>(p1, out, KT);
}